// Round 6
// baseline (205.549 us; speedup 1.0000x reference)
//
#include <hip/hip_runtime.h>
#include <hip/hip_bf16.h>

// SelfAttention N=8192, D_IN=512, D_K=64 (fp32 io).
// R5 = R4 resubmitted verbatim (R4 bench was lost to GPUAcquisitionTimeout).
//   prep_w : W fp32 -> wh/wl bf16 [192][512]
//   qkv3   : 512 blocks x 256thr; X fp32 loaded + split inline; Q scaled 1/8
//            split hi/lo row-major; K split hi/lo K'-frag order; V bf16 V'-frag order.
//   attn4  : grid 1024 = 64 qblk x 16 ks; 4 waves; wave: 32 q x 512 keys.
//            Swapped QK^T (scores lane-local, q = lane&15), defer-max THR=8,
//            P -> per-wave LDS (stride 72) -> b128 A-frags, rowsum via
//            MFMA-with-ones on truncated P, PV bf16. Partials: num bf16, den/M fp32.
//   merge16: combine 16 key-split partials.

#define N_TOK 8192
#define D_INN 512
#define DK    64

typedef __attribute__((ext_vector_type(8))) short bf16x8;
typedef __attribute__((ext_vector_type(4))) float f32x4;

static __device__ __forceinline__ unsigned f2bf_u(float f) {
  union { float f; unsigned u; } v; v.f = f;
  return (v.u + 0x7FFFu + ((v.u >> 16) & 1u)) >> 16;
}
static __device__ __forceinline__ unsigned short f2bf(float f) { return (unsigned short)f2bf_u(f); }
static __device__ __forceinline__ float bf2f(unsigned short h) {
  union { unsigned u; float f; } v; v.u = ((unsigned)h) << 16; return v.f;
}
static __device__ __forceinline__ unsigned truncpk(float a, float b) {
  union { float f; unsigned u; } x, y; x.f = a; y.f = b;
  return (x.u >> 16) | (y.u & 0xFFFF0000u);
}
static __device__ __forceinline__ void split2(float a, float b, unsigned& hi, unsigned& lo) {
  unsigned ha = f2bf_u(a), hb = f2bf_u(b);
  float ra = a - bf2f((unsigned short)ha);
  float rb = b - bf2f((unsigned short)hb);
  hi = ha | (hb << 16);
  lo = f2bf_u(ra) | (f2bf_u(rb) << 16);
}

// ---------------- split W ----------------
__global__ __launch_bounds__(256) void prep_w(
    const float* __restrict__ Wq, const float* __restrict__ Wk, const float* __restrict__ Wv,
    unsigned short* __restrict__ wh, unsigned short* __restrict__ wl) {
  int t = blockIdx.x * 256 + threadIdx.x;
  if (t >= 192 * 512) return;
  const float* src = (t < 64 * 512) ? Wq : ((t < 128 * 512) ? Wk : Wv);
  float x = src[t & (64 * 512 - 1)];
  unsigned short h = f2bf(x);
  wh[t] = h;
  wl[t] = f2bf(x - bf2f(h));
}

// ---------------- QKV projection (inline X split) ----------------
// grid 512 (16 tokens each) x 256 thr. Wave w handles col-tile dq = w*16 of Q,K,V.
__global__ __launch_bounds__(256, 2) void qkv3(
    const float* __restrict__ X,
    const unsigned short* __restrict__ wh, const unsigned short* __restrict__ wl,
    unsigned short* __restrict__ qhp, unsigned short* __restrict__ qlp,
    unsigned short* __restrict__ kph, unsigned short* __restrict__ kpl,
    unsigned short* __restrict__ vp) {
  const int tid = threadIdx.x, w = tid >> 6, l = tid & 63;
  const int l15 = l & 15, g = l >> 4;
  const int t0 = blockIdx.x * 16;
  const int dq = w * 16;

  f32x4 aq = {0.f, 0.f, 0.f, 0.f}, ak = aq, av = aq;

  for (int kc = 0; kc < D_INN; kc += 32) {
    const float* xp = X + (t0 + l15) * D_INN + kc + g * 8;
    float4 x0 = *(const float4*)xp;
    float4 x1 = *(const float4*)(xp + 4);
    union { unsigned u[4]; bf16x8 v; } ahu, alu;
    split2(x0.x, x0.y, ahu.u[0], alu.u[0]);
    split2(x0.z, x0.w, ahu.u[1], alu.u[1]);
    split2(x1.x, x1.y, ahu.u[2], alu.u[2]);
    split2(x1.z, x1.w, ahu.u[3], alu.u[3]);
    bf16x8 ah = ahu.v, al = alu.v;

    const int wq_off = (dq + l15) * D_INN + kc + g * 8;
    const int wk_off = (64 + dq + l15) * D_INN + kc + g * 8;
    const int wv_off = (128 + dq + l15) * D_INN + kc + g * 8;
    bf16x8 bqh = *(const bf16x8*)(wh + wq_off);
    bf16x8 bql = *(const bf16x8*)(wl + wq_off);
    bf16x8 bkh = *(const bf16x8*)(wh + wk_off);
    bf16x8 bkl = *(const bf16x8*)(wl + wk_off);
    bf16x8 bvh = *(const bf16x8*)(wh + wv_off);
    aq = __builtin_amdgcn_mfma_f32_16x16x32_bf16(ah, bqh, aq, 0, 0, 0);
    aq = __builtin_amdgcn_mfma_f32_16x16x32_bf16(ah, bql, aq, 0, 0, 0);
    aq = __builtin_amdgcn_mfma_f32_16x16x32_bf16(al, bqh, aq, 0, 0, 0);
    ak = __builtin_amdgcn_mfma_f32_16x16x32_bf16(ah, bkh, ak, 0, 0, 0);
    ak = __builtin_amdgcn_mfma_f32_16x16x32_bf16(ah, bkl, ak, 0, 0, 0);
    ak = __builtin_amdgcn_mfma_f32_16x16x32_bf16(al, bkh, ak, 0, 0, 0);
    av = __builtin_amdgcn_mfma_f32_16x16x32_bf16(ah, bvh, av, 0, 0, 0);
    av = __builtin_amdgcn_mfma_f32_16x16x32_bf16(al, bvh, av, 0, 0, 0);
  }

  // Q: fold 1/8 scale, split hi/lo, row-major [8192][64]
#pragma unroll
  for (int r = 0; r < 4; r++) {
    float v = aq[r] * 0.125f;
    int row = t0 + g * 4 + r;
    unsigned short h = f2bf(v);
    qhp[row * DK + dq + l15] = h;
    qlp[row * DK + dq + l15] = f2bf(v - bf2f(h));
  }
  // K: split hi/lo, K'-frag order
#pragma unroll
  for (int r = 0; r < 4; r++) {
    float v = ak[r];
    int t = t0 + g * 4 + r;
    int d = dq + l15;
    int off = (t >> 5) * 2048 + ((t >> 4) & 1) * 1024 + (d >> 5) * 512 +
              ((t & 15) + (((d >> 3) & 3) << 4)) * 8 + (d & 7);
    unsigned short h = f2bf(v);
    kph[off] = h;
    kpl[off] = f2bf(v - bf2f(h));
  }
  // V: single bf16, V'-frag order, 4 consecutive tokens packed (8B)
  {
    int tg = t0 + g * 4;
    int d = dq + l15;
    int off = (tg >> 5) * 2048 + (d >> 4) * 512 +
              (((d & 15) + (((tg >> 3) & 3) << 4))) * 8 + (tg & 7);
    uint2 pk;
    pk.x = f2bf_u(av[0]) | (f2bf_u(av[1]) << 16);
    pk.y = f2bf_u(av[2]) | (f2bf_u(av[3]) << 16);
    *(uint2*)(vp + off) = pk;
  }
}

// ---------------- flash attention ----------------
// grid 1024 = 64 qblocks x 16 key-splits; 256 thr (4 waves); wave: 32 q x 512 keys.
__global__ __launch_bounds__(256, 4) void attn4(
    const unsigned short* __restrict__ qhp, const unsigned short* __restrict__ qlp,
    const unsigned short* __restrict__ kph, const unsigned short* __restrict__ kpl,
    const unsigned short* __restrict__ vp,
    unsigned short* __restrict__ pnb, float* __restrict__ pden, float* __restrict__ pM) {
  __shared__ unsigned short P_lds[4 * 2 * 16 * 72];

  const int tid = threadIdx.x, w = tid >> 6, l = tid & 63;
  const int l15 = l & 15, g = l >> 4;
  const int qblk = blockIdx.x >> 4, ks = blockIdx.x & 15;
  const int wq0 = qblk * 128 + w * 32;

  // Q fragments (B-operand of swapped QK^T)
  bf16x8 qhf[2][2], qlf[2][2];
#pragma unroll
  for (int u = 0; u < 2; u++)
#pragma unroll
    for (int c = 0; c < 2; c++) {
      int row = wq0 + u * 16 + l15;
      qhf[u][c] = *(const bf16x8*)(qhp + row * DK + c * 32 + g * 8);
      qlf[u][c] = *(const bf16x8*)(qlp + row * DK + c * 32 + g * 8);
    }

  const short onec = (short)0x3F80;
  const bf16x8 ones = {onec, onec, onec, onec, onec, onec, onec, onec};

  f32x4 accO[2][4], accL[2];
  float m[2] = {-1e30f, -1e30f};
#pragma unroll
  for (int u = 0; u < 2; u++) {
    accL[u] = f32x4{0.f, 0.f, 0.f, 0.f};
#pragma unroll
    for (int ds = 0; ds < 4; ds++) accO[u][ds] = f32x4{0.f, 0.f, 0.f, 0.f};
  }

  for (int kt = ks * 512; kt < ks * 512 + 512; kt += 64) {
    const int kti = kt >> 5;

    // S^T = K Q^T (scores: col = q = lane&15, row = key via (g, reg))
    f32x4 st[2][4];
#pragma unroll
    for (int s = 0; s < 4; s++) {
      bf16x8 khf[2], klf[2];
#pragma unroll
      for (int c = 0; c < 2; c++) {
        const int off = (kti + (s >> 1)) * 2048 + (s & 1) * 1024 + c * 512 + l * 8;
        khf[c] = *(const bf16x8*)(kph + off);
        klf[c] = *(const bf16x8*)(kpl + off);
      }
      __builtin_amdgcn_s_setprio(1);
#pragma unroll
      for (int u = 0; u < 2; u++) {
        f32x4 sa = {0.f, 0.f, 0.f, 0.f};
        sa = __builtin_amdgcn_mfma_f32_16x16x32_bf16(khf[0], qhf[u][0], sa, 0, 0, 0);
        sa = __builtin_amdgcn_mfma_f32_16x16x32_bf16(khf[1], qhf[u][1], sa, 0, 0, 0);
        sa = __builtin_amdgcn_mfma_f32_16x16x32_bf16(khf[0], qlf[u][0], sa, 0, 0, 0);
        sa = __builtin_amdgcn_mfma_f32_16x16x32_bf16(khf[1], qlf[u][1], sa, 0, 0, 0);
        sa = __builtin_amdgcn_mfma_f32_16x16x32_bf16(klf[0], qhf[u][0], sa, 0, 0, 0);
        sa = __builtin_amdgcn_mfma_f32_16x16x32_bf16(klf[1], qhf[u][1], sa, 0, 0, 0);
        st[u][s] = sa;
      }
      __builtin_amdgcn_s_setprio(0);
    }

    // V fragments (global, coalesced; used after softmax)
    bf16x8 vb[4][2];
#pragma unroll
    for (int ds = 0; ds < 4; ds++)
#pragma unroll
      for (int c = 0; c < 2; c++)
        vb[ds][c] = *(const bf16x8*)(vp + (kti + c) * 2048 + ds * 512 + l * 8);

    bf16x8 pa[2][2];
#pragma unroll
    for (int u = 0; u < 2; u++) {
      // row-max: in-lane fmax + 2 cross-g shuffles (q stays = lane&15)
      float t0m = fmaxf(fmaxf(st[u][0][0], st[u][0][1]), fmaxf(st[u][0][2], st[u][0][3]));
      float t1m = fmaxf(fmaxf(st[u][1][0], st[u][1][1]), fmaxf(st[u][1][2], st[u][1][3]));
      float t2m = fmaxf(fmaxf(st[u][2][0], st[u][2][1]), fmaxf(st[u][2][2], st[u][2][3]));
      float t3m = fmaxf(fmaxf(st[u][3][0], st[u][3][1]), fmaxf(st[u][3][2], st[u][3][3]));
      float tm = fmaxf(fmaxf(t0m, t1m), fmaxf(t2m, t3m));
      tm = fmaxf(tm, __shfl_xor(tm, 16, 64));
      tm = fmaxf(tm, __shfl_xor(tm, 32, 64));
      if (__any(tm > m[u] + 8.f)) {  // defer-max (THR=8)
        float mn = fmaxf(m[u], tm);
        float fac = __expf(m[u] - mn);
        m[u] = mn;
#pragma unroll
        for (int r = 0; r < 4; r++) {
          float fr = __shfl(fac, g * 4 + r, 64);
          accL[u][r] *= fr;
#pragma unroll
          for (int ds = 0; ds < 4; ds++) accO[u][ds][r] *= fr;
        }
      }
      // P = exp(S - m); lane (q=l15, g) owns keys kappa = s*16 + g*4 + r.
      // Per-wave LDS transpose: write row q / col kappa, read b128 A-frag.
      const int base = ((w * 2 + u) * 16 + l15) * 72;
#pragma unroll
      for (int s = 0; s < 4; s++) {
        float p0 = __expf(st[u][s][0] - m[u]);
        float p1 = __expf(st[u][s][1] - m[u]);
        float p2 = __expf(st[u][s][2] - m[u]);
        float p3 = __expf(st[u][s][3] - m[u]);
        *(unsigned*)&P_lds[base + s * 16 + g * 4]     = truncpk(p0, p1);
        *(unsigned*)&P_lds[base + s * 16 + g * 4 + 2] = truncpk(p2, p3);
      }
#pragma unroll
      for (int c = 0; c < 2; c++)
        pa[u][c] = *(const bf16x8*)&P_lds[base + c * 32 + g * 8];
      // row-sum on the SAME truncated P (num/den bias cancels)
      accL[u] = __builtin_amdgcn_mfma_f32_16x16x32_bf16(pa[u][0], ones, accL[u], 0, 0, 0);
      accL[u] = __builtin_amdgcn_mfma_f32_16x16x32_bf16(pa[u][1], ones, accL[u], 0, 0, 0);
    }

    // PV
    __builtin_amdgcn_s_setprio(1);
#pragma unroll
    for (int ds = 0; ds < 4; ds++)
#pragma unroll
      for (int u = 0; u < 2; u++) {
        accO[u][ds] = __builtin_amdgcn_mfma_f32_16x16x32_bf16(pa[u][0], vb[ds][0], accO[u][ds], 0, 0, 0);
        accO[u][ds] = __builtin_amdgcn_mfma_f32_16x16x32_bf16(pa[u][1], vb[ds][1], accO[u][ds], 0, 0, 0);
      }
    __builtin_amdgcn_s_setprio(0);
  }

  // write per-(qblock, key-split) partials (num bf16, den/M fp32)
#pragma unroll
  for (int u = 0; u < 2; u++) {
#pragma unroll
    for (int ds = 0; ds < 4; ds++)
#pragma unroll
      for (int r = 0; r < 4; r++)
        pnb[(size_t)ks * (N_TOK * DK) + (wq0 + u * 16 + g * 4 + r) * DK + ds * 16 + l15] =
            f2bf(accO[u][ds][r]);
    if (l15 == 0) {
#pragma unroll
      for (int r = 0; r < 4; r++) pden[ks * N_TOK + wq0 + u * 16 + g * 4 + r] = accL[u][r];
    }
    if (g == 0) pM[ks * N_TOK + wq0 + u * 16 + l15] = m[u];
  }
}

// ---------------- merge 16 key-split partials ----------------
__global__ __launch_bounds__(256) void merge16(
    const unsigned short* __restrict__ pnb, const float* __restrict__ pden,
    const float* __restrict__ pM, float* __restrict__ out) {
  int i = blockIdx.x * 256 + threadIdx.x;
  int q = i >> 6, d = i & 63;
  float M = -1e30f;
#pragma unroll
  for (int s = 0; s < 16; s++) M = fmaxf(M, pM[s * N_TOK + q]);
  float num = 0.f, den = 0.f;
#pragma unroll
  for (int s = 0; s < 16; s++) {
    float e = __expf(pM[s * N_TOK + q] - M);
    num += bf2f(pnb[(size_t)s * (N_TOK * DK) + q * DK + d]) * e;
    den += pden[s * N_TOK + q] * e;
  }
  out[i] = num / den;
}

// ---------------- host launch ----------------
extern "C" void kernel_launch(void* const* d_in, const int* in_sizes, int n_in,
                              void* d_out, int out_size, void* d_ws, size_t ws_size,
                              hipStream_t stream) {
  (void)in_sizes; (void)n_in; (void)out_size; (void)ws_size;
  const float* X  = (const float*)d_in[0];
  const float* Wq = (const float*)d_in[1];
  const float* Wk = (const float*)d_in[2];
  const float* Wv = (const float*)d_in[3];

  char* base = (char*)d_ws;
  unsigned short* pnb = (unsigned short*)(base);                  // 16 MB [16][8192][64] bf16
  unsigned short* qhp = (unsigned short*)(base + 16777216);       // 1 MB
  unsigned short* qlp = (unsigned short*)(base + 17825792);       // 1 MB
  unsigned short* kph = (unsigned short*)(base + 18874368);       // 1 MB
  unsigned short* kpl = (unsigned short*)(base + 19922944);       // 1 MB
  unsigned short* vp  = (unsigned short*)(base + 20971520);       // 1 MB
  // [22020096, 23068672): wh/wl during qkv3, then pden/pM during attn4/merge16
  unsigned short* wh  = (unsigned short*)(base + 22020096);       // 192 KB
  unsigned short* wl  = (unsigned short*)(base + 22216704);       // 192 KB
  float* pden = (float*)(base + 22020096);                        // 512 KB (aliases wh/wl)
  float* pM   = (float*)(base + 22544384);                        // 512 KB

  prep_w<<<384, 256, 0, stream>>>(Wq, Wk, Wv, wh, wl);
  qkv3<<<N_TOK / 16, 256, 0, stream>>>(X, wh, wl, qhp, qlp, kph, kpl, vp);
  attn4<<<1024, 256, 0, stream>>>(qhp, qlp, kph, kpl, vp, pnb, pden, pM);
  merge16<<<(N_TOK * DK) / 256, 256, 0, stream>>>(pnb, pden, pM, (float*)d_out);
}

// Round 7
// 148.018 us; speedup vs baseline: 1.3887x; 1.3887x over previous
//
#include <hip/hip_runtime.h>
#include <hip/hip_bf16.h>

// SelfAttention N=8192, D_IN=512, D_K=64 (fp32 io).
// R6 = R5 with: (a) attn4 launch_bounds reverted to (256,2) — R5's (256,4)
// forced VGPR 92->64 and spilled 264MB to scratch (FETCH 196MB), 49.6->109us.
// Natural 92-reg allocation already allows 4 waves/SIMD; grid=1024 supplies
// the waves. (b) prep_w deleted: qkv3 splits W from fp32 in-register.
//   qkv3   : 512 blocks x 256thr; X and W fp32 loaded + split inline; Q scaled
//            1/8 split hi/lo row-major; K split hi/lo K'-frag order; V bf16 V'-frag.
//   attn4  : grid 1024 = 64 qblk x 16 ks; 4 waves; wave: 32 q x 512 keys.
//            Swapped QK^T (scores lane-local, q = lane&15), defer-max THR=8,
//            P -> per-wave LDS (stride 72) -> b128 A-frags, rowsum via
//            MFMA-with-ones on truncated P, PV bf16. Partials: num bf16, den/M fp32.
//   merge16: combine 16 key-split partials.

#define N_TOK 8192
#define D_INN 512
#define DK    64

typedef __attribute__((ext_vector_type(8))) short bf16x8;
typedef __attribute__((ext_vector_type(4))) float f32x4;

static __device__ __forceinline__ unsigned f2bf_u(float f) {
  union { float f; unsigned u; } v; v.f = f;
  return (v.u + 0x7FFFu + ((v.u >> 16) & 1u)) >> 16;
}
static __device__ __forceinline__ unsigned short f2bf(float f) { return (unsigned short)f2bf_u(f); }
static __device__ __forceinline__ float bf2f(unsigned short h) {
  union { unsigned u; float f; } v; v.u = ((unsigned)h) << 16; return v.f;
}
static __device__ __forceinline__ unsigned truncpk(float a, float b) {
  union { float f; unsigned u; } x, y; x.f = a; y.f = b;
  return (x.u >> 16) | (y.u & 0xFFFF0000u);
}
static __device__ __forceinline__ void split2(float a, float b, unsigned& hi, unsigned& lo) {
  unsigned ha = f2bf_u(a), hb = f2bf_u(b);
  float ra = a - bf2f((unsigned short)ha);
  float rb = b - bf2f((unsigned short)hb);
  hi = ha | (hb << 16);
  lo = f2bf_u(ra) | (f2bf_u(rb) << 16);
}
static __device__ __forceinline__ void split8(const float* p, bf16x8& hi, bf16x8& lo) {
  float4 a = *(const float4*)p;
  float4 b = *(const float4*)(p + 4);
  union { unsigned u[4]; bf16x8 v; } H, L;
  split2(a.x, a.y, H.u[0], L.u[0]);
  split2(a.z, a.w, H.u[1], L.u[1]);
  split2(b.x, b.y, H.u[2], L.u[2]);
  split2(b.z, b.w, H.u[3], L.u[3]);
  hi = H.v; lo = L.v;
}
static __device__ __forceinline__ bf16x8 round8(const float* p) {
  float4 a = *(const float4*)p;
  float4 b = *(const float4*)(p + 4);
  union { unsigned u[4]; bf16x8 v; } H;
  H.u[0] = f2bf_u(a.x) | (f2bf_u(a.y) << 16);
  H.u[1] = f2bf_u(a.z) | (f2bf_u(a.w) << 16);
  H.u[2] = f2bf_u(b.x) | (f2bf_u(b.y) << 16);
  H.u[3] = f2bf_u(b.z) | (f2bf_u(b.w) << 16);
  return H.v;
}

// ---------------- QKV projection (inline X and W split) ----------------
// grid 512 (16 tokens each) x 256 thr. Wave w handles col-tile dq = w*16 of Q,K,V.
__global__ __launch_bounds__(256, 2) void qkv3(
    const float* __restrict__ X,
    const float* __restrict__ Wq, const float* __restrict__ Wk, const float* __restrict__ Wv,
    unsigned short* __restrict__ qhp, unsigned short* __restrict__ qlp,
    unsigned short* __restrict__ kph, unsigned short* __restrict__ kpl,
    unsigned short* __restrict__ vp) {
  const int tid = threadIdx.x, w = tid >> 6, l = tid & 63;
  const int l15 = l & 15, g = l >> 4;
  const int t0 = blockIdx.x * 16;
  const int dq = w * 16;

  f32x4 aq = {0.f, 0.f, 0.f, 0.f}, ak = aq, av = aq;

  for (int kc = 0; kc < D_INN; kc += 32) {
    bf16x8 ah, al;
    split8(X + (t0 + l15) * D_INN + kc + g * 8, ah, al);

    const int woff = (dq + l15) * D_INN + kc + g * 8;
    bf16x8 bqh, bql, bkh, bkl;
    split8(Wq + woff, bqh, bql);
    split8(Wk + woff, bkh, bkl);
    bf16x8 bvh = round8(Wv + woff);

    aq = __builtin_amdgcn_mfma_f32_16x16x32_bf16(ah, bqh, aq, 0, 0, 0);
    aq = __builtin_amdgcn_mfma_f32_16x16x32_bf16(ah, bql, aq, 0, 0, 0);
    aq = __builtin_amdgcn_mfma_f32_16x16x32_bf16(al, bqh, aq, 0, 0, 0);
    ak = __builtin_amdgcn_mfma_f32_16x16x32_bf16(ah, bkh, ak, 0, 0, 0);
    ak = __builtin_amdgcn_mfma_f32_16x16x32_bf16(ah, bkl, ak, 0, 0, 0);
    ak = __builtin_amdgcn_mfma_f32_16x16x32_bf16(al, bkh, ak, 0, 0, 0);
    av = __builtin_amdgcn_mfma_f32_16x16x32_bf16(ah, bvh, av, 0, 0, 0);
    av = __builtin_amdgcn_mfma_f32_16x16x32_bf16(al, bvh, av, 0, 0, 0);
  }

  // Q: fold 1/8 scale, split hi/lo, row-major [8192][64]
#pragma unroll
  for (int r = 0; r < 4; r++) {
    float v = aq[r] * 0.125f;
    int row = t0 + g * 4 + r;
    unsigned short h = f2bf(v);
    qhp[row * DK + dq + l15] = h;
    qlp[row * DK + dq + l15] = f2bf(v - bf2f(h));
  }
  // K: split hi/lo, K'-frag order
#pragma unroll
  for (int r = 0; r < 4; r++) {
    float v = ak[r];
    int t = t0 + g * 4 + r;
    int d = dq + l15;
    int off = (t >> 5) * 2048 + ((t >> 4) & 1) * 1024 + (d >> 5) * 512 +
              ((t & 15) + (((d >> 3) & 3) << 4)) * 8 + (d & 7);
    unsigned short h = f2bf(v);
    kph[off] = h;
    kpl[off] = f2bf(v - bf2f(h));
  }
  // V: single bf16, V'-frag order, 4 consecutive tokens packed (8B)
  {
    int tg = t0 + g * 4;
    int d = dq + l15;
    int off = (tg >> 5) * 2048 + (d >> 4) * 512 +
              (((d & 15) + (((tg >> 3) & 3) << 4))) * 8 + (tg & 7);
    uint2 pk;
    pk.x = f2bf_u(av[0]) | (f2bf_u(av[1]) << 16);
    pk.y = f2bf_u(av[2]) | (f2bf_u(av[3]) << 16);
    *(uint2*)(vp + off) = pk;
  }
}

// ---------------- flash attention ----------------
// grid 1024 = 64 qblocks x 16 key-splits; 256 thr (4 waves); wave: 32 q x 512 keys.
__global__ __launch_bounds__(256, 2) void attn4(
    const unsigned short* __restrict__ qhp, const unsigned short* __restrict__ qlp,
    const unsigned short* __restrict__ kph, const unsigned short* __restrict__ kpl,
    const unsigned short* __restrict__ vp,
    unsigned short* __restrict__ pnb, float* __restrict__ pden, float* __restrict__ pM) {
  __shared__ unsigned short P_lds[4 * 2 * 16 * 72];

  const int tid = threadIdx.x, w = tid >> 6, l = tid & 63;
  const int l15 = l & 15, g = l >> 4;
  const int qblk = blockIdx.x >> 4, ks = blockIdx.x & 15;
  const int wq0 = qblk * 128 + w * 32;

  // Q fragments (B-operand of swapped QK^T)
  bf16x8 qhf[2][2], qlf[2][2];
#pragma unroll
  for (int u = 0; u < 2; u++)
#pragma unroll
    for (int c = 0; c < 2; c++) {
      int row = wq0 + u * 16 + l15;
      qhf[u][c] = *(const bf16x8*)(qhp + row * DK + c * 32 + g * 8);
      qlf[u][c] = *(const bf16x8*)(qlp + row * DK + c * 32 + g * 8);
    }

  const short onec = (short)0x3F80;
  const bf16x8 ones = {onec, onec, onec, onec, onec, onec, onec, onec};

  f32x4 accO[2][4], accL[2];
  float m[2] = {-1e30f, -1e30f};
#pragma unroll
  for (int u = 0; u < 2; u++) {
    accL[u] = f32x4{0.f, 0.f, 0.f, 0.f};
#pragma unroll
    for (int ds = 0; ds < 4; ds++) accO[u][ds] = f32x4{0.f, 0.f, 0.f, 0.f};
  }

  for (int kt = ks * 512; kt < ks * 512 + 512; kt += 64) {
    const int kti = kt >> 5;

    // S^T = K Q^T (scores: col = q = lane&15, row = key via (g, reg))
    f32x4 st[2][4];
#pragma unroll
    for (int s = 0; s < 4; s++) {
      bf16x8 khf[2], klf[2];
#pragma unroll
      for (int c = 0; c < 2; c++) {
        const int off = (kti + (s >> 1)) * 2048 + (s & 1) * 1024 + c * 512 + l * 8;
        khf[c] = *(const bf16x8*)(kph + off);
        klf[c] = *(const bf16x8*)(kpl + off);
      }
      __builtin_amdgcn_s_setprio(1);
#pragma unroll
      for (int u = 0; u < 2; u++) {
        f32x4 sa = {0.f, 0.f, 0.f, 0.f};
        sa = __builtin_amdgcn_mfma_f32_16x16x32_bf16(khf[0], qhf[u][0], sa, 0, 0, 0);
        sa = __builtin_amdgcn_mfma_f32_16x16x32_bf16(khf[1], qhf[u][1], sa, 0, 0, 0);
        sa = __builtin_amdgcn_mfma_f32_16x16x32_bf16(khf[0], qlf[u][0], sa, 0, 0, 0);
        sa = __builtin_amdgcn_mfma_f32_16x16x32_bf16(khf[1], qlf[u][1], sa, 0, 0, 0);
        sa = __builtin_amdgcn_mfma_f32_16x16x32_bf16(klf[0], qhf[u][0], sa, 0, 0, 0);
        sa = __builtin_amdgcn_mfma_f32_16x16x32_bf16(klf[1], qhf[u][1], sa, 0, 0, 0);
        st[u][s] = sa;
      }
      __builtin_amdgcn_s_setprio(0);
    }

    // V fragments (global, coalesced; used after softmax)
    bf16x8 vb[4][2];
#pragma unroll
    for (int ds = 0; ds < 4; ds++)
#pragma unroll
      for (int c = 0; c < 2; c++)
        vb[ds][c] = *(const bf16x8*)(vp + (kti + c) * 2048 + ds * 512 + l * 8);

    bf16x8 pa[2][2];
#pragma unroll
    for (int u = 0; u < 2; u++) {
      // row-max: in-lane fmax + 2 cross-g shuffles (q stays = lane&15)
      float t0m = fmaxf(fmaxf(st[u][0][0], st[u][0][1]), fmaxf(st[u][0][2], st[u][0][3]));
      float t1m = fmaxf(fmaxf(st[u][1][0], st[u][1][1]), fmaxf(st[u][1][2], st[u][1][3]));
      float t2m = fmaxf(fmaxf(st[u][2][0], st[u][2][1]), fmaxf(st[u][2][2], st[u][2][3]));
      float t3m = fmaxf(fmaxf(st[u][3][0], st[u][3][1]), fmaxf(st[u][3][2], st[u][3][3]));
      float tm = fmaxf(fmaxf(t0m, t1m), fmaxf(t2m, t3m));
      tm = fmaxf(tm, __shfl_xor(tm, 16, 64));
      tm = fmaxf(tm, __shfl_xor(tm, 32, 64));
      if (__any(tm > m[u] + 8.f)) {  // defer-max (THR=8)
        float mn = fmaxf(m[u], tm);
        float fac = __expf(m[u] - mn);
        m[u] = mn;
#pragma unroll
        for (int r = 0; r < 4; r++) {
          float fr = __shfl(fac, g * 4 + r, 64);
          accL[u][r] *= fr;
#pragma unroll
          for (int ds = 0; ds < 4; ds++) accO[u][ds][r] *= fr;
        }
      }
      // P = exp(S - m); lane (q=l15, g) owns keys kappa = s*16 + g*4 + r.
      // Per-wave LDS transpose: write row q / col kappa, read b128 A-frag.
      const int base = ((w * 2 + u) * 16 + l15) * 72;
#pragma unroll
      for (int s = 0; s < 4; s++) {
        float p0 = __expf(st[u][s][0] - m[u]);
        float p1 = __expf(st[u][s][1] - m[u]);
        float p2 = __expf(st[u][s][2] - m[u]);
        float p3 = __expf(st[u][s][3] - m[u]);
        *(unsigned*)&P_lds[base + s * 16 + g * 4]     = truncpk(p0, p1);
        *(unsigned*)&P_lds[base + s * 16 + g * 4 + 2] = truncpk(p2, p3);
      }
#pragma unroll
      for (int c = 0; c < 2; c++)
        pa[u][c] = *(const bf16x8*)&P_lds[base + c * 32 + g * 8];
      // row-sum on the SAME truncated P (num/den bias cancels)
      accL[u] = __builtin_amdgcn_mfma_f32_16x16x32_bf16(pa[u][0], ones, accL[u], 0, 0, 0);
      accL[u] = __builtin_amdgcn_mfma_f32_16x16x32_bf16(pa[u][1], ones, accL[u], 0, 0, 0);
    }

    // PV
    __builtin_amdgcn_s_setprio(1);
#pragma unroll
    for (int ds = 0; ds < 4; ds++)
#pragma unroll
      for (int u = 0; u < 2; u++) {
        accO[u][ds] = __builtin_amdgcn_mfma_f32_16x16x32_bf16(pa[u][0], vb[ds][0], accO[u][ds], 0, 0, 0);
        accO[u][ds] = __builtin_amdgcn_mfma_f32_16x16x32_bf16(pa[u][1], vb[ds][1], accO[u][ds], 0, 0, 0);
      }
    __builtin_amdgcn_s_setprio(0);
  }

  // write per-(qblock, key-split) partials (num bf16, den/M fp32)
#pragma unroll
  for (int u = 0; u < 2; u++) {
#pragma unroll
    for (int ds = 0; ds < 4; ds++)
#pragma unroll
      for (int r = 0; r < 4; r++)
        pnb[(size_t)ks * (N_TOK * DK) + (wq0 + u * 16 + g * 4 + r) * DK + ds * 16 + l15] =
            f2bf(accO[u][ds][r]);
    if (l15 == 0) {
#pragma unroll
      for (int r = 0; r < 4; r++) pden[ks * N_TOK + wq0 + u * 16 + g * 4 + r] = accL[u][r];
    }
    if (g == 0) pM[ks * N_TOK + wq0 + u * 16 + l15] = m[u];
  }
}

// ---------------- merge 16 key-split partials ----------------
__global__ __launch_bounds__(256) void merge16(
    const unsigned short* __restrict__ pnb, const float* __restrict__ pden,
    const float* __restrict__ pM, float* __restrict__ out) {
  int i = blockIdx.x * 256 + threadIdx.x;
  int q = i >> 6, d = i & 63;
  float M = -1e30f;
#pragma unroll
  for (int s = 0; s < 16; s++) M = fmaxf(M, pM[s * N_TOK + q]);
  float num = 0.f, den = 0.f;
#pragma unroll
  for (int s = 0; s < 16; s++) {
    float e = __expf(pM[s * N_TOK + q] - M);
    num += bf2f(pnb[(size_t)s * (N_TOK * DK) + q * DK + d]) * e;
    den += pden[s * N_TOK + q] * e;
  }
  out[i] = num / den;
}

// ---------------- host launch ----------------
extern "C" void kernel_launch(void* const* d_in, const int* in_sizes, int n_in,
                              void* d_out, int out_size, void* d_ws, size_t ws_size,
                              hipStream_t stream) {
  (void)in_sizes; (void)n_in; (void)out_size; (void)ws_size;
  const float* X  = (const float*)d_in[0];
  const float* Wq = (const float*)d_in[1];
  const float* Wk = (const float*)d_in[2];
  const float* Wv = (const float*)d_in[3];

  char* base = (char*)d_ws;
  unsigned short* pnb = (unsigned short*)(base);                  // 16 MB [16][8192][64] bf16
  unsigned short* qhp = (unsigned short*)(base + 16777216);       // 1 MB
  unsigned short* qlp = (unsigned short*)(base + 17825792);       // 1 MB
  unsigned short* kph = (unsigned short*)(base + 18874368);       // 1 MB
  unsigned short* kpl = (unsigned short*)(base + 19922944);       // 1 MB
  unsigned short* vp  = (unsigned short*)(base + 20971520);       // 1 MB
  float* pden = (float*)(base + 22020096);                        // 512 KB
  float* pM   = (float*)(base + 22544384);                        // 512 KB

  qkv3<<<N_TOK / 16, 256, 0, stream>>>(X, Wq, Wk, Wv, qhp, qlp, kph, kpl, vp);
  attn4<<<1024, 256, 0, stream>>>(qhp, qlp, kph, kpl, vp, pnb, pden, pM);
  merge16<<<(N_TOK * DK) / 256, 256, 0, stream>>>(pnb, pden, pM, (float*)d_out);
}